// Round 1
// baseline (9.748 us; speedup 1.0000x reference)
//
#include <hip/hip_runtime.h>

// Problem constants (from reference): B,I,N,D,C = 1024,256,2048,32,32
#define B_ 1024
#define I_ 256
#define N_ 2048
#define D_ 32
#define C_ 32

// Only out_nodes[:, -1] and out2 (which uses gathered[:, -1]) are returned.
// The einsum contracts over c per-n, so only n = N-1 is live. Compute just that.
//
// Layout: block = 256 threads = 8 batch rows x 32 lanes.
//   phase 1: stage W[N-1] (32x32, padded to 33 cols -> conflict-free column reads),
//            b[N-1], W_out, idx[N-1] in LDS.
//   phase 2: lane c gathers g[row][c] (relu'd conv if idx<I else h0 read).
//   phase 3: lane d computes relu(dot(g, W[N-1,d,:]) + b[N-1,d]); lane 0 does out2.
__global__ __launch_bounds__(256) void prnn_last_kernel(
    const float* __restrict__ x, const float* __restrict__ h0,
    const float* __restrict__ conv_w, const float* __restrict__ conv_b,
    const float* __restrict__ W, const float* __restrict__ bvec,
    const float* __restrict__ W_out, const float* __restrict__ b_out,
    const int* __restrict__ idx,
    float* __restrict__ out_nodes, float* __restrict__ out2)
{
    __shared__ float Ws[D_][C_ + 1];   // +1 pad: Ws[d][c] column reads hit distinct banks
    __shared__ float gs[8][C_];
    __shared__ float bs[D_];
    __shared__ float wouts[C_];
    __shared__ int   idxs[C_];

    const int tid = threadIdx.x;

    // Stage the (tiny) shared operands.
    for (int t = tid; t < D_ * C_; t += 256) {
        Ws[t / C_][t % C_] = W[(size_t)(N_ - 1) * D_ * C_ + t];
    }
    if (tid < D_) bs[tid] = bvec[(size_t)(N_ - 1) * D_ + tid];
    if (tid < C_) { wouts[tid] = W_out[tid]; idxs[tid] = idx[(size_t)(N_ - 1) * C_ + tid]; }
    __syncthreads();

    const int row = tid >> 5;          // 0..7 within block
    const int lane = tid & 31;         // c (gather phase) / d (dot phase)
    const int b = blockIdx.x * 8 + row;

    // Gather g[c] = buf[b, idx[N-1, c]]
    {
        const int j = idxs[lane];
        float v;
        if (j < I_) {
            v = fmaf(x[(size_t)b * I_ + j], conv_w[j], conv_b[j]);
            v = v > 0.f ? v : 0.f;     // relu'd conv region
        } else {
            v = h0[(size_t)b * (N_ * D_) + (size_t)(j - I_)];  // raw h0 region
        }
        gs[row][lane] = v;
    }
    __syncthreads();

    // out_nodes[:, -1][b, d]
    float acc = bs[lane];
    #pragma unroll
    for (int c = 0; c < C_; ++c) acc = fmaf(gs[row][c], Ws[lane][c], acc);
    acc = acc > 0.f ? acc : 0.f;
    out_nodes[(size_t)b * D_ + lane] = acc;

    // out2[b] (one lane per row; 32 MACs, negligible)
    if (lane == 0) {
        float a2 = b_out[0];
        #pragma unroll
        for (int c = 0; c < C_; ++c) a2 = fmaf(gs[row][c], wouts[c], a2);
        out2[b] = a2 > 0.f ? a2 : 0.f;
    }
}

extern "C" void kernel_launch(void* const* d_in, const int* in_sizes, int n_in,
                              void* d_out, int out_size, void* d_ws, size_t ws_size,
                              hipStream_t stream) {
    const float* x      = (const float*)d_in[0];
    const float* h0     = (const float*)d_in[1];
    const float* conv_w = (const float*)d_in[2];
    const float* conv_b = (const float*)d_in[3];
    const float* W      = (const float*)d_in[4];
    const float* bvec   = (const float*)d_in[5];
    const float* W_out  = (const float*)d_in[6];
    const float* b_out  = (const float*)d_in[7];
    const int*   idx    = (const int*)d_in[8];

    float* out       = (float*)d_out;            // (B, D) flat = 32768 floats
    float* out2      = out + (size_t)B_ * D_;    // (B, 1) flat = 1024 floats

    prnn_last_kernel<<<B_ / 8, 256, 0, stream>>>(
        x, h0, conv_w, conv_b, W, bvec, W_out, b_out, idx, out, out2);
}

// Round 2
// 9.709 us; speedup vs baseline: 1.0040x; 1.0040x over previous
//
#include <hip/hip_runtime.h>

// Problem constants (from reference): B,I,N,D,C = 1024,256,2048,32,32
#define B_ 1024
#define I_ 256
#define N_ 2048
#define D_ 32
#define C_ 32

// Only out_nodes[:, -1] and out2 (both depend solely on gathered[:, N-1, :])
// are returned -> compute just the n = N-1 slice.
//
// Barrier-free, LDS-free version: each 32-lane half-wave owns one batch row.
//   lane c gathers g[c] (kept in a register)
//   lane d holds W[N-1, d, 0:32] in 32 VGPRs (coalesced float4 row loads)
//   dot via 32 width-32 shuffle-broadcast FMAs; out2 via shfl_xor reduction.
// Critical path: idx load -> x gather -> 32 FMAs -> store. No __syncthreads.
__global__ __launch_bounds__(256) void prnn_last_kernel(
    const float* __restrict__ x, const float* __restrict__ h0,
    const float* __restrict__ conv_w, const float* __restrict__ conv_b,
    const float* __restrict__ W, const float* __restrict__ bvec,
    const float* __restrict__ W_out, const float* __restrict__ b_out,
    const int* __restrict__ idx,
    float* __restrict__ out_nodes, float* __restrict__ out2)
{
    const int tid  = threadIdx.x;
    const int row  = tid >> 5;          // 0..7 within block (half-wave granularity)
    const int lane = tid & 31;          // c (gather) / d (dot)
    const int b    = blockIdx.x * 8 + row;

    // --- longest dependent chain first: idx -> gathered value ---
    const int j = idx[(size_t)(N_ - 1) * C_ + lane];
    float g;
    if (j < I_) {
        float v = fmaf(x[(size_t)b * I_ + j], conv_w[j], conv_b[j]);
        g = v > 0.f ? v : 0.f;          // relu'd conv region
    } else {
        g = h0[(size_t)b * (N_ * D_) + (size_t)(j - I_)];  // raw h0 region
    }

    // --- independent loads: W row d, bias, W_out (issue in parallel with gather) ---
    float wr[C_];
    const float* Wrow = W + (size_t)(N_ - 1) * D_ * C_ + (size_t)lane * C_;
    #pragma unroll
    for (int q = 0; q < C_ / 4; ++q) {
        float4 v = reinterpret_cast<const float4*>(Wrow)[q];
        wr[4 * q + 0] = v.x; wr[4 * q + 1] = v.y;
        wr[4 * q + 2] = v.z; wr[4 * q + 3] = v.w;
    }
    float acc  = bvec[(size_t)(N_ - 1) * D_ + lane];
    float wout = W_out[lane];
    float bo   = b_out[0];

    // --- out_nodes[:, -1][b, d]: shuffle-broadcast dot, width 32 ---
    #pragma unroll
    for (int c = 0; c < C_; ++c)
        acc = fmaf(__shfl(g, c, 32), wr[c], acc);
    out_nodes[(size_t)b * D_ + lane] = acc > 0.f ? acc : 0.f;

    // --- out2[b]: reduce g * W_out over the 32-lane group ---
    float p = g * wout;
    #pragma unroll
    for (int m = 16; m; m >>= 1) p += __shfl_xor(p, m, 32);
    if (lane == 0) out2[b] = fmaxf(p + bo, 0.f);
}

extern "C" void kernel_launch(void* const* d_in, const int* in_sizes, int n_in,
                              void* d_out, int out_size, void* d_ws, size_t ws_size,
                              hipStream_t stream) {
    const float* x      = (const float*)d_in[0];
    const float* h0     = (const float*)d_in[1];
    const float* conv_w = (const float*)d_in[2];
    const float* conv_b = (const float*)d_in[3];
    const float* W      = (const float*)d_in[4];
    const float* bvec   = (const float*)d_in[5];
    const float* W_out  = (const float*)d_in[6];
    const float* b_out  = (const float*)d_in[7];
    const int*   idx    = (const int*)d_in[8];

    float* out  = (float*)d_out;             // (B, D) flat = 32768 floats
    float* out2 = out + (size_t)B_ * D_;     // (B,)   flat = 1024 floats

    prnn_last_kernel<<<B_ / 8, 256, 0, stream>>>(
        x, h0, conv_w, conv_b, W, bvec, W_out, b_out, idx, out, out2);
}